// Round 1
// 294.133 us; speedup vs baseline: 1.0000x; 1.0000x over previous
//
#include <hip/hip_runtime.h>
#include <math.h>

#define N_NODES 50000
#define N_EDGES 800000
#define EP (N_EDGES + N_NODES)   // 850000 edges incl. self loops
#define NEG 0.2f
#define SCAN_BLOCKS 49           // ceil(50000/1024)

typedef __attribute__((ext_vector_type(8))) short bf16x8;
typedef __attribute__((ext_vector_type(4))) float f32x4;
typedef __attribute__((ext_vector_type(2))) float f32x2;

// bf16 round-to-nearest-even from fp32
static __device__ __forceinline__ unsigned short bf16_rn(float f) {
    union { float f; unsigned int u; } v; v.f = f;
    unsigned int u = v.u;
    unsigned int r = (u + 0x7FFFu + ((u >> 16) & 1u)) >> 16;
    return (unsigned short)r;
}
static __device__ __forceinline__ float bf16_tof(unsigned short u) {
    union { unsigned int u; float f; } v; v.u = ((unsigned int)u) << 16;
    return v.f;
}
// unpack 2 bf16 (packed in a dword) -> f32x2 {low, high}
static __device__ __forceinline__ f32x2 bf2_unpack(unsigned int u) {
    union { unsigned int i; float f; } a, b;
    a.i = u << 16; b.i = u & 0xFFFF0000u;
    return (f32x2){a.f, b.f};
}

// ---------------- CSR build ----------------

__global__ void k_hist(const int* __restrict__ ei, int* __restrict__ counts) {
    int e = blockIdx.x * 256 + threadIdx.x;
    if (e >= EP) return;
    int d = (e < N_EDGES) ? ei[N_EDGES + e] : (e - N_EDGES);
    atomicAdd(&counts[d], 1);
}

__global__ void k_scan_block(const int* __restrict__ counts, int* __restrict__ excl,
                             int* __restrict__ bsums) {
    __shared__ int wsum[4];
    int b = blockIdx.x, t = threadIdx.x;
    int lane = t & 63, w = t >> 6;
    int i0 = b * 1024 + t * 4;
    int v0 = (i0 + 0 < N_NODES) ? counts[i0 + 0] : 0;
    int v1 = (i0 + 1 < N_NODES) ? counts[i0 + 1] : 0;
    int v2 = (i0 + 2 < N_NODES) ? counts[i0 + 2] : 0;
    int v3 = (i0 + 3 < N_NODES) ? counts[i0 + 3] : 0;
    int s = v0 + v1 + v2 + v3;
    int incl = s;
    #pragma unroll
    for (int d = 1; d < 64; d <<= 1) {
        int u = __shfl_up(incl, d);
        if (lane >= d) incl += u;
    }
    if (lane == 63) wsum[w] = incl;
    __syncthreads();
    if (t == 0) {
        int run = 0;
        #pragma unroll
        for (int i = 0; i < 4; ++i) { int x = wsum[i]; wsum[i] = run; run += x; }
        bsums[b] = run;   // block total
    }
    __syncthreads();
    int base = wsum[w] + incl - s;   // exclusive prefix of this thread's chunk
    if (i0 + 0 < N_NODES) excl[i0 + 0] = base;
    if (i0 + 1 < N_NODES) excl[i0 + 1] = base + v0;
    if (i0 + 2 < N_NODES) excl[i0 + 2] = base + v0 + v1;
    if (i0 + 3 < N_NODES) excl[i0 + 3] = base + v0 + v1 + v2;
}

// scan_mid folded in: every block wave-scans the 49 block sums itself
__global__ void k_scan_add(int* __restrict__ row_ptr, const int* __restrict__ bsums) {
    __shared__ int soff;
    int b = blockIdx.x, t = threadIdx.x;
    if (t < 64) {
        int v = (t < SCAN_BLOCKS) ? bsums[t] : 0;
        int incl = v;
        #pragma unroll
        for (int d = 1; d < 64; d <<= 1) {
            int u = __shfl_up(incl, d);
            if (t >= d) incl += u;
        }
        if (t == b) soff = incl - v;   // exclusive prefix at block b
    }
    __syncthreads();
    int off = soff;
    int i0 = b * 1024 + t * 4;
    #pragma unroll
    for (int j = 0; j < 4; ++j)
        if (i0 + j < N_NODES) row_ptr[i0 + j] += off;
    if (b == 0 && t == 0) row_ptr[N_NODES] = EP;
}

__global__ void k_scatter(const int* __restrict__ ei, const int* __restrict__ row_ptr,
                          int* __restrict__ fill, int* __restrict__ colb) {
    int e = blockIdx.x * 256 + threadIdx.x;
    if (e >= EP) return;
    int s, d;
    if (e < N_EDGES) { s = ei[e]; d = ei[N_EDGES + e]; }
    else             { s = e - N_EDGES; d = s; }
    int pos = row_ptr[d] + atomicAdd(&fill[d], 1);
    colb[pos] = s;
}

// ---------------- W1 -> MFMA B-fragment order (pi-permuted), bf16 ----------------
// Tile nt, lane l handles W column n = (l&15)*16 + nt  (pi-permutation so each
// lane's 16 accumulator tiles cover 16 CONSECUTIVE output channels -> b128
// stores + in-lane alpha dots in the GEMM epilogue).
// k = c*32 + (l>>4)*8 + j.
__global__ void k_cvtWfrag(const float* __restrict__ W1, bf16x8* __restrict__ Wfrag) {
    int ft = blockIdx.x * 256 + threadIdx.x;   // 8192 frag-lanes
    int c = ft >> 10, rem = ft & 1023;
    int nt = rem >> 6, l = rem & 63;
    int n = (l & 15) * 16 + nt;
    int k0 = c * 32 + (l >> 4) * 8;
    bf16x8 f;
    #pragma unroll
    for (int j = 0; j < 8; ++j)
        f[j] = (short)bf16_rn(W1[(k0 + j) * 256 + n]);
    Wfrag[ft] = f;
}

// ---------------- Layer 1 GEMM via bf16 MFMA + fused attention logits ----------------
// xp1b[50000][256] bf16 = (x @ W1), fp32 accumulate; as1/ad1 from fp32 accs.
// Block = 256 threads (4 waves), 64 rows/block; wave w owns ONE 16-row m-group
// (doubles resident waves vs the 2-group/wave version -> better latency hiding).
//   A frag lane l: A[m=l&15][k0+(l>>4)*8+j]
//   C/D lane l, reg r: row=(l>>4)*4+r; channels (l&15)*16 + nt  (pi-permuted)
#define GM_GRID 782   // ceil(50000/64)
__global__ __launch_bounds__(256) void
k_gemm1m(const float* __restrict__ x, const bf16x8* __restrict__ Wfrag,
         unsigned short* __restrict__ xp1b,
         const float* __restrict__ asrc, const float* __restrict__ adst,
         float* __restrict__ as1, float* __restrict__ ad1) {
    __shared__ bf16x8 lds[1024];   // one chunk of B frags: 16 KB
    int t = threadIdx.x, l = t & 63, w = t >> 6;
    int rowbase = blockIdx.x * 64 + w * 16;
    int m = l & 15, kg = l >> 4;

    f32x4 acc[16];
    #pragma unroll
    for (int nt = 0; nt < 16; ++nt)
        acc[nt] = (f32x4){0.f, 0.f, 0.f, 0.f};

    int r0 = rowbase + m;
    if (r0 > N_NODES - 1) r0 = N_NODES - 1;   // clamp (results unused)
    const float4* x4 = (const float4*)x;

    for (int c = 0; c < 8; ++c) {
        __syncthreads();   // previous chunk's B reads done before overwrite
        const bf16x8* src = Wfrag + c * 1024;
        #pragma unroll
        for (int q = 0; q < 4; ++q)
            lds[q * 256 + t] = src[q * 256 + t];
        __syncthreads();

        int kb = (c * 32 + kg * 8) >> 2;       // float4 col index
        float4 xa0 = x4[r0 * 64 + kb], xb0 = x4[r0 * 64 + kb + 1];
        bf16x8 aF0;
        aF0[0] = (short)bf16_rn(xa0.x); aF0[1] = (short)bf16_rn(xa0.y);
        aF0[2] = (short)bf16_rn(xa0.z); aF0[3] = (short)bf16_rn(xa0.w);
        aF0[4] = (short)bf16_rn(xb0.x); aF0[5] = (short)bf16_rn(xb0.y);
        aF0[6] = (short)bf16_rn(xb0.z); aF0[7] = (short)bf16_rn(xb0.w);

        #pragma unroll
        for (int nt = 0; nt < 16; ++nt) {
            bf16x8 bF = lds[nt * 64 + l];
            acc[nt] = __builtin_amdgcn_mfma_f32_16x16x32_bf16(aF0, bF, acc[nt], 0, 0, 0);
        }
    }

    // epilogue: lane holds channels cbase*16 + nt (nt=0..15) of rows rq*4+reg
    int cbase = l & 15, rq = l >> 4;
    // attention vectors for this lane's 16 channels (head = cbase>>1)
    float asV[16], adV[16];
    #pragma unroll
    for (int q = 0; q < 4; ++q) {
        float4 sa = ((const float4*)asrc)[cbase * 4 + q];
        float4 da = ((const float4*)adst)[cbase * 4 + q];
        asV[q * 4 + 0] = sa.x; asV[q * 4 + 1] = sa.y; asV[q * 4 + 2] = sa.z; asV[q * 4 + 3] = sa.w;
        adV[q * 4 + 0] = da.x; adV[q * 4 + 1] = da.y; adV[q * 4 + 2] = da.z; adV[q * 4 + 3] = da.w;
    }
    #pragma unroll
    for (int reg = 0; reg < 4; ++reg) {
        int gr = rowbase + rq * 4 + reg;
        unsigned int ob[8];
        float ps = 0.f, pd = 0.f;
        #pragma unroll
        for (int q = 0; q < 8; ++q) {
            float v0 = acc[2 * q][reg], v1 = acc[2 * q + 1][reg];
            ob[q] = (unsigned int)bf16_rn(v0) | ((unsigned int)bf16_rn(v1) << 16);
            ps = fmaf(v0, asV[2 * q], ps);     ps = fmaf(v1, asV[2 * q + 1], ps);
            pd = fmaf(v0, adV[2 * q], pd);     pd = fmaf(v1, adV[2 * q + 1], pd);
        }
        ps += __shfl_xor(ps, 1);
        pd += __shfl_xor(pd, 1);
        if (gr < N_NODES) {
            uint4* dst = (uint4*)(xp1b + gr * 256 + cbase * 16);
            dst[0] = make_uint4(ob[0], ob[1], ob[2], ob[3]);
            dst[1] = make_uint4(ob[4], ob[5], ob[6], ob[7]);
            if ((l & 1) == 0) {
                as1[gr * 8 + (cbase >> 1)] = ps;
                ad1[gr * 8 + (cbase >> 1)] = pd;
            }
        }
    }
}

// ---------------- fused layer-1 softmax-aggregate + ReLU + layer-2 proj/logits ----
// One wave per node; HALF-WAVE edge split: lanes 0-31 take edge j, lanes 32-63
// take edge j+1. Each lane loads 16B (uint4 = 8 bf16 channels) of the source
// row: c0 = (l&31)*8 .. +7.  Halves the exp/addr/colb/as1 instruction count
// per edge and uses dwordx4 gathers; same 512B/edge of traffic.
__global__ void k_agg1(const ushort4* __restrict__ xpb, const float* __restrict__ as1,
                       const float* __restrict__ ad1, const int* __restrict__ row_ptr,
                       const int* __restrict__ colb, const float* __restrict__ b1,
                       const float* __restrict__ W2, const float* __restrict__ as2w,
                       const float* __restrict__ ad2w,
                       float* __restrict__ xp2, float* __restrict__ as2,
                       float* __restrict__ ad2) {
    int t = threadIdx.x, l = t & 63, w = t >> 6;
    int n = blockIdx.x * 4 + w;
    int hl = l & 31;                 // half-lane
    int half = l >> 5;               // 0: even edge, 1: odd edge
    int hidx = hl >> 2;              // head for channels 8*hl .. 8*hl+7
    float adn = ad1[n * 8 + hidx];
    int start = row_ptr[n], end = row_ptr[n + 1];
    const uint4* xp4 = (const uint4*)xpb;
    f32x2 acc0 = {0.f, 0.f}, acc1 = {0.f, 0.f}, acc2 = {0.f, 0.f}, acc3 = {0.f, 0.f};
    float den = 0.f;
    int j = start;
    for (; j + 4 <= end; j += 4) {
        int jj0 = j + half, jj1 = j + 2 + half;
        int s0 = colb[jj0], s1 = colb[jj1];
        uint4 r0 = xp4[s0 * 32 + hl];
        uint4 r1 = xp4[s1 * 32 + hl];
        float e0 = as1[s0 * 8 + hidx] + adn;
        float e1 = as1[s1 * 8 + hidx] + adn;
        e0 = (e0 > 0.f) ? e0 : NEG * e0;
        e1 = (e1 > 0.f) ? e1 : NEG * e1;
        float p0 = __expf(e0), p1 = __expf(e1);
        den += p0 + p1;
        f32x2 q0 = {p0, p0}, q1 = {p1, p1};
        acc0 += q0 * bf2_unpack(r0.x);  acc1 += q0 * bf2_unpack(r0.y);
        acc2 += q0 * bf2_unpack(r0.z);  acc3 += q0 * bf2_unpack(r0.w);
        acc0 += q1 * bf2_unpack(r1.x);  acc1 += q1 * bf2_unpack(r1.y);
        acc2 += q1 * bf2_unpack(r1.z);  acc3 += q1 * bf2_unpack(r1.w);
    }
    for (; j < end; j += 2) {
        int jj = j + half;
        bool v = jj < end;
        int s = colb[v ? jj : start];
        uint4 r = xp4[s * 32 + hl];
        float e = as1[s * 8 + hidx] + adn;
        e = (e > 0.f) ? e : NEG * e;
        float p = v ? __expf(e) : 0.f;
        den += p;
        f32x2 q = {p, p};
        acc0 += q * bf2_unpack(r.x);  acc1 += q * bf2_unpack(r.y);
        acc2 += q * bf2_unpack(r.z);  acc3 += q * bf2_unpack(r.w);
    }
    // combine the two half-wave partial sums (both halves end with the total)
    acc0[0] += __shfl_xor(acc0[0], 32); acc0[1] += __shfl_xor(acc0[1], 32);
    acc1[0] += __shfl_xor(acc1[0], 32); acc1[1] += __shfl_xor(acc1[1], 32);
    acc2[0] += __shfl_xor(acc2[0], 32); acc2[1] += __shfl_xor(acc2[1], 32);
    acc3[0] += __shfl_xor(acc3[0], 32); acc3[1] += __shfl_xor(acc3[1], 32);
    den += __shfl_xor(den, 32);

    // epilogue: lane covers channels c0 = 8*hl .. +7
    float inv = 1.f / den;
    float4 ba = ((const float4*)b1)[hl * 2];
    float4 bb = ((const float4*)b1)[hl * 2 + 1];
    float o0 = fmaxf(acc0[0] * inv + ba.x, 0.f);
    float o1 = fmaxf(acc0[1] * inv + ba.y, 0.f);
    float o2 = fmaxf(acc1[0] * inv + ba.z, 0.f);
    float o3 = fmaxf(acc1[1] * inv + ba.w, 0.f);
    float o4 = fmaxf(acc2[0] * inv + bb.x, 0.f);
    float o5 = fmaxf(acc2[1] * inv + bb.y, 0.f);
    float o6 = fmaxf(acc3[0] * inv + bb.z, 0.f);
    float o7 = fmaxf(acc3[1] * inv + bb.w, 0.f);
    // fused proj2: W2 row-major (256,2); lane covers rows c0..c0+7
    const float4* W4 = (const float4*)W2;
    float4 wa = W4[hl * 4 + 0];   // rows c0+0, c0+1
    float4 wb = W4[hl * 4 + 1];   // rows c0+2, c0+3
    float4 wc = W4[hl * 4 + 2];   // rows c0+4, c0+5
    float4 wd = W4[hl * 4 + 3];   // rows c0+6, c0+7
    float d0 = o0 * wa.x + o1 * wa.z + o2 * wb.x + o3 * wb.z
             + o4 * wc.x + o5 * wc.z + o6 * wd.x + o7 * wd.z;
    float d1 = o0 * wa.y + o1 * wa.w + o2 * wb.y + o3 * wb.w
             + o4 * wc.y + o5 * wc.w + o6 * wd.y + o7 * wd.w;
    #pragma unroll
    for (int m = 1; m < 32; m <<= 1) {
        d0 += __shfl_xor(d0, m);
        d1 += __shfl_xor(d1, m);
    }
    if (l == 0) {
        xp2[2 * n] = d0;
        xp2[2 * n + 1] = d1;
        as2[n] = d0 * as2w[0] + d1 * as2w[1];
        ad2[n] = d0 * ad2w[0] + d1 * ad2w[1];
    }
}

// ---------------- fused segment-softmax + aggregate, layer 2 (2 channels) ----------------
// 16 lanes per node (16 nodes/block): avg degree ~17 so 64-lane waves were ~27%
// lane-utilized; 16-lane tiles quarter the wave count.
__global__ void k_agg2(const float* __restrict__ xp2, const float* __restrict__ as2,
                       const float* __restrict__ ad2, const int* __restrict__ row_ptr,
                       const int* __restrict__ colb, const float* __restrict__ b2,
                       float* __restrict__ out) {
    int t = threadIdx.x;
    int g = t >> 4, lane = t & 15;
    int n = blockIdx.x * 16 + g;
    int start = row_ptr[n], end = row_ptr[n + 1];
    float adn = ad2[n];
    float a0 = 0.f, a1 = 0.f, den = 0.f;
    for (int j = start + lane; j < end; j += 16) {
        int s = colb[j];
        float e = as2[s] + adn;
        e = (e > 0.f) ? e : NEG * e;
        float p = __expf(e);
        den += p;
        float2 xv = ((const float2*)xp2)[s];
        a0 = fmaf(p, xv.x, a0);
        a1 = fmaf(p, xv.y, a1);
    }
    #pragma unroll
    for (int m = 1; m < 16; m <<= 1) {
        a0 += __shfl_xor(a0, m);
        a1 += __shfl_xor(a1, m);
        den += __shfl_xor(den, m);
    }
    if (lane == 0) {
        out[2 * n] = a0 / den + b2[0];
        out[2 * n + 1] = a1 / den + b2[1];
    }
}

extern "C" void kernel_launch(void* const* d_in, const int* in_sizes, int n_in,
                              void* d_out, int out_size, void* d_ws, size_t ws_size,
                              hipStream_t stream) {
    const float* x     = (const float*)d_in[0];
    const int*   ei    = (const int*)d_in[1];
    const float* W1    = (const float*)d_in[2];
    const float* asrc1 = (const float*)d_in[3];
    const float* adst1 = (const float*)d_in[4];
    const float* b1    = (const float*)d_in[5];
    const float* W2    = (const float*)d_in[6];
    const float* asrc2 = (const float*)d_in[7];
    const float* adst2 = (const float*)d_in[8];
    const float* b2    = (const float*)d_in[9];
    float* out = (float*)d_out;

    char* ws = (char*)d_ws;
    unsigned short* xp1b = (unsigned short*)(ws + 0);        // 25,600,000 B (bf16)
    bf16x8* Wfrag  = (bf16x8*)(ws + 25600000);      //    131,072 B (B frags)
    float* as1     = (float*)(ws + 102400000);      //  1,600,000 B
    float* ad1     = (float*)(ws + 104000000);      //  1,600,000 B
    float* xp2     = (float*)(ws + 105600000);      //    400,000 B
    float* as2     = (float*)(ws + 106000000);      //    200,000 B
    float* ad2     = (float*)(ws + 106200000);      //    200,000 B
    int*   counts  = (int*)  (ws + 106400000);      //    200,000 B
    int*   fill    = (int*)  (ws + 106600000);      //    200,000 B (contig w/ counts)
    int*   row_ptr = (int*)  (ws + 106800000);      //    200,064 B
    int*   colb    = (int*)  (ws + 107000064);      //  3,400,000 B
    int*   bsums   = (int*)  (ws + 110400064);      //        256 B

    hipMemsetAsync(counts, 0, 400000, stream);      // counts + fill

    int egrid = (EP + 255) / 256;
    k_hist      <<<egrid,       256, 0, stream>>>(ei, counts);
    k_scan_block<<<SCAN_BLOCKS, 256, 0, stream>>>(counts, row_ptr, bsums);
    k_scan_add  <<<SCAN_BLOCKS, 256, 0, stream>>>(row_ptr, bsums);
    k_scatter   <<<egrid,       256, 0, stream>>>(ei, row_ptr, fill, colb);

    k_cvtWfrag  <<<32,     256, 0, stream>>>(W1, Wfrag);
    k_gemm1m    <<<GM_GRID, 256, 0, stream>>>(x, Wfrag, xp1b, asrc1, adst1, as1, ad1);
    k_agg1      <<<12500,  256, 0, stream>>>((const ushort4*)xp1b, as1, ad1, row_ptr, colb,
                                             b1, W2, asrc2, adst2, xp2, as2, ad2);
    k_agg2      <<<3125,   256, 0, stream>>>(xp2, as2, ad2, row_ptr, colb, b2, out);
}